// Round 11
// baseline (864.501 us; speedup 1.0000x reference)
//
#include <hip/hip_runtime.h>
#include <hip/hip_bf16.h>

// Problem constants (fixed by setup_inputs)
#define BB_  64
#define TT_  512
#define FF_  1024
#define HH_  31
#define GG_  124   // 4*H
#define FUT_ 16
#define TTOT_ 528  // T + future
#define OUT_ROW_ ((size_t)TTOT_ * FF_)   // per-batch stride in output

// ---- workspace layout (float indices) ----
#define PRE1_OFF ((size_t)0)                              // [512][64][128]
#define H2A_OFF  (PRE1_OFF + (size_t)TT_*64*128)          // [528*64][32]
#define WT_OFF   (H2A_OFF  + (size_t)TTOT_*64*32)         // [31][1024]
#define MV_OFF   (WT_OFF   + 31*1024)                     // [124][32]
#define FLG_OFF  (MV_OFF   + 124*32)                      // 128 ints of flags

#define NPROD 512           // producer blocks (one timestep each), blk 0..511
#define KBLK  64            // k2-role blocks, blk 512..575
#define NBLK  (NPROD + KBLK)

__device__ __forceinline__ float rdlane(float v, int k) {
    return __uint_as_float(__builtin_amdgcn_readlane(__float_as_uint(v), k));
}
__device__ __forceinline__ int aload_acq(int* p) {
    return __hip_atomic_load(p, __ATOMIC_ACQUIRE, __HIP_MEMORY_SCOPE_AGENT);
}
__device__ __forceinline__ void aadd_rel(int* p, int v) {
    __hip_atomic_fetch_add(p, v, __ATOMIC_RELEASE, __HIP_MEMORY_SCOPE_AGENT);
}

// repeat macros
#define REP31(M) M(0) M(1) M(2) M(3) M(4) M(5) M(6) M(7) M(8) M(9) \
                 M(10) M(11) M(12) M(13) M(14) M(15) M(16) M(17) M(18) M(19) \
                 M(20) M(21) M(22) M(23) M(24) M(25) M(26) M(27) M(28) M(29) M(30)
#define REP16E(M) M(0) M(2) M(4) M(6) M(8) M(10) M(12) M(14) \
                  M(16) M(18) M(20) M(22) M(24) M(26) M(28) M(30)
#define REP15O(M) M(1) M(3) M(5) M(7) M(9) M(11) M(13) M(15) \
                  M(17) M(19) M(21) M(23) M(25) M(27) M(29)

// ---------------- K_ZERO: clear flag region (separate launch -> visible to fused) ----
__global__ void k_zero(int* flg) {
    if (threadIdx.x < 128) flg[threadIdx.x] = 0;
}

// ---------------- K_FUSED: producers (k1+k0+k0b) overlapped with k2 ----------------
// PLAIN launch (no cooperative API -- R10's failure was the coop call tripping
// graph capture, not the sync design). Co-residency by capacity arithmetic:
// 576 blocks x 24KB LDS -> 6 blocks/CU LDS-capped (1536 slots) and 8 wave-capped
// (2048 slots) >> 576, so ALL blocks are resident from dispatch; the only
// waiters (k2 role) wait on producers that are guaranteed running -> no deadlock.
// Flags: flg[0..63] = pre1 group-of-8 counters (==8 when timesteps 8g..8g+7 are
// in memory); flg[64] = mv_cnt (==16 when Mv ready). Producers signal with
// {__syncthreads() drains all waves' stores to this XCD's L2} + {tid0 agent-scope
// release add -> L2 writeback}; k2 polls with agent-scope acquire loads (L1/L2
// invalidate) and touches the data only after the flag -> no stale-cache hazard.
// All numeric bodies are verbatim from the R9-verified kernels (k1=R0 body,
// k2=R6 body) -> output bit-identical (absmax must stay 0.001953125).
__global__ __launch_bounds__(256) void k_fused(
    const float* __restrict__ X,
    const float* __restrict__ Wih1,
    const float* __restrict__ Whh1,
    const float* __restrict__ Wih2,
    const float* __restrict__ Whh2,
    const float* __restrict__ bih1, const float* __restrict__ bhh1,
    const float* __restrict__ bih2, const float* __restrict__ bhh2,
    const float* __restrict__ Wlin,
    const float* __restrict__ blin,
    float* __restrict__ pre1,
    float* __restrict__ h2a,
    float* __restrict__ WT,
    float* __restrict__ Mv,
    int*   __restrict__ flg)
{
    __shared__ __align__(16) float smem[6144];   // 24KB, role-aliased
    int* pre_grp = flg;          // [64]
    int* mv_cnt  = flg + 64;
    const int blk = blockIdx.x;
    const int tid = threadIdx.x;

    if (blk < NPROD) {
        // ================= PRODUCER: k1 for timestep t (R0 body, verbatim) ====
        const int t = blk;                            // 0..511
        {
            float (*xs)[64]  = (float(*)[64])smem;           // [32][64]
            float (*ws)[128] = (float(*)[128])(smem + 2048); // [32][128]
            const int tcol = tid & 31, trow = tid >> 5;
            const int c0 = tcol * 4, r0 = trow * 8;

            float4 acc[8];
#pragma unroll
            for (int r = 0; r < 8; r++) acc[r] = make_float4(0.f, 0.f, 0.f, 0.f);

            for (int kc = 0; kc < 32; ++kc) {
                const int k0 = kc * 32;
#pragma unroll
                for (int p = 0; p < 2; p++) {
                    int i = tid + p * 256;
                    int r = i >> 3, f = i & 7;
                    float4 v = *(const float4*)(X + (size_t)r * TT_ * FF_ + (size_t)t * FF_ + k0 + f * 4);
                    xs[f * 4 + 0][r] = v.x; xs[f * 4 + 1][r] = v.y;
                    xs[f * 4 + 2][r] = v.z; xs[f * 4 + 3][r] = v.w;
                }
#pragma unroll
                for (int p = 0; p < 4; p++) {
                    int i = tid + p * 256;
                    int g = i >> 3, f = i & 7;
                    float4 v = make_float4(0.f, 0.f, 0.f, 0.f);
                    if (g < GG_) v = *(const float4*)(Wih1 + (size_t)g * FF_ + k0 + f * 4);
                    ws[f * 4 + 0][g] = v.x; ws[f * 4 + 1][g] = v.y;
                    ws[f * 4 + 2][g] = v.z; ws[f * 4 + 3][g] = v.w;
                }
                __syncthreads();
#pragma unroll
                for (int k = 0; k < 32; k++) {
                    float4 wv = *(const float4*)&ws[k][c0];
                    float4 xa = *(const float4*)&xs[k][r0];
                    float4 xb = *(const float4*)&xs[k][r0 + 4];
                    float rx[8] = {xa.x, xa.y, xa.z, xa.w, xb.x, xb.y, xb.z, xb.w};
#pragma unroll
                    for (int r = 0; r < 8; r++) {
                        acc[r].x += rx[r] * wv.x; acc[r].y += rx[r] * wv.y;
                        acc[r].z += rx[r] * wv.z; acc[r].w += rx[r] * wv.w;
                    }
                }
                __syncthreads();
            }
            float bias[4];
#pragma unroll
            for (int cc = 0; cc < 4; cc++) {
                int c = c0 + cc;
                bias[cc] = (c < GG_) ? (bih1[c] + bhh1[c]) : 0.0f;
            }
#pragma unroll
            for (int r = 0; r < 8; r++) {
                int m = t * 64 + r0 + r;
                float4 o = acc[r];
                o.x += bias[0]; o.y += bias[1]; o.z += bias[2]; o.w += bias[3];
                *(float4*)(pre1 + (size_t)m * 128 + c0) = o;
            }
        }
        // signal: barrier drains all waves' pre1 stores to this XCD's L2;
        // release-add writes the L2 back so any XCD sees the data.
        __syncthreads();
        if (tid == 0) aadd_rel(&pre_grp[t >> 3], 1);

        // -------- extras: k0 (WT transpose; consumed only by k3 next launch,
        // kernel boundary is the fence -> no flag) / k0b (Mv; k2 waits on flag)
        if (t < 124) {
            int i = t * 256 + tid;          // 124*256 = 31744 = 1024*31
            int j = i / 31;
            int k = i - j * 31;
            WT[k * 1024 + j] = Wlin[i];
        } else if (t < 140) {
            int idx = (t - 124) * 256 + tid;
            if (idx < GG_ * 32) {
                int g = idx >> 5, k = idx & 31;
                const float* wr = Wih1 + (size_t)g * FF_;
                float acc = 0.0f;
                if (k < 31) {
#pragma unroll 8
                    for (int j = 0; j < FF_; j++) acc += wr[j] * Wlin[j * 31 + k];
                } else {
#pragma unroll 8
                    for (int j = 0; j < FF_; j++) acc += wr[j] * blin[j];
                }
                Mv[idx] = acc;
            }
            __syncthreads();
            if (tid == 0) aadd_rel(mv_cnt, 1);
        }
        return;
    }

    // ===================== K2-ROLE BLOCK (blk 512..575) =======================
    if (tid >= 128) {
        // barrier-count skeleton: must match real path exactly
        // (1 prologue + 511 main + 1 tail + 32 future = 545)
        __syncthreads();
        for (int t = 0; t < TT_ - 1; t++) __syncthreads();
        __syncthreads();
        for (int s = 0; s < FUT_; s++) { __syncthreads(); __syncthreads(); }
        return;
    }

    {
        const int L  = tid;               // 0..127
        const int bb = blk - NPROD;       // 0..63
        const int j  = L & 63;
        const int gc = (L < GG_) ? L : (GG_ - 1);
        const bool isg = (gc >= 62 && gc < 93);
        const bool selhi = (j >= 32);
        const int sidx = selhi ? (j - 32) : j;
        float (*gA)[128] = (float(*)[128])smem;          // [2][128]
        float (*g2)[128] = (float(*)[128])(smem + 256);  // [2][128]

#define WLOAD(k) float w1_##k  = Whh1[gc * 31 + k]; \
                 float wi2_##k = Wih2[gc * 31 + k]; \
                 float wh2_##k = Whh2[gc * 31 + k];
        REP31(WLOAD)
#undef WLOAD
#define WPIN(k) asm("" : "+v"(w1_##k), "+v"(wi2_##k), "+v"(wh2_##k));
        REP31(WPIN)
#undef WPIN

        const float b2c = bih2[gc] + bhh2[gc];
        float hv = 0.0f, cv = 0.0f;
        int rg = 0;   // pre1 groups known-ready

        // wait for group 0 (timesteps 0..7) before prologue loads
        while (aload_acq(&pre_grp[0]) < 8) __builtin_amdgcn_s_sleep(8);
        rg = 1;
        float cur0 = pre1[(size_t)bb * 128 + L];
        float pnxt = pre1[((size_t)1 * 64 + bb) * 128 + L];
        float pnx2 = pre1[((size_t)2 * 64 + bb) * 128 + L];
        {
            float pa0 = cur0, pa1 = 0.0f;
#define DPE(k) { float hk = rdlane(hv, 32 + k); pa0 += w1_##k * hk; }
#define DPO(k) { float hk = rdlane(hv, 32 + k); pa1 += w1_##k * hk; }
            REP16E(DPE)
            REP15O(DPO)
#undef DPE
#undef DPO
            float a = pa0 + pa1;
            float z = isg ? (2.0f * a) : a;
            float s = 1.0f / (1.0f + __expf(-z));
            gA[1][L] = isg ? (2.0f * s - 1.0f) : s;
        }
        __syncthreads();
        {
            const float* gsrc = &gA[1][0];
            float ig = gsrc[sidx];
            float fg = gsrc[sidx + 31];
            float gg = gsrc[sidx + 62];
            float og = gsrc[sidx + 93];
            float cvn = fg * cv + ig * gg;
            float e = __expf(-2.0f * cvn);
            float hvn = og * (2.0f / (1.0f + e) - 1.0f);
            cv = selhi ? cvn : 0.0f;
            hv = selhi ? hvn : 0.0f;
        }

        for (int t = 0; t < TT_ - 1; t++) {
            const int pb = t & 1;
            const float cur = pnxt;
            pnxt = pnx2;
            if (t + 3 < TT_) {
                const int gneed = (t + 3) >> 3;
                while (rg <= gneed) {
                    if (aload_acq(&pre_grp[rg]) == 8) rg++;
                    else __builtin_amdgcn_s_sleep(2);
                }
                pnx2 = pre1[((size_t)(t + 3) * 64 + bb) * 128 + L];
            }

            float bi0 = b2c, bi1 = 0.0f, bh0 = 0.0f, bh1 = 0.0f;
            float pa0 = cur, pa1 = 0.0f;
#define DME(k) { float h1k = rdlane(hv, 32 + k); float h2k = rdlane(hv, k); \
                 bi0 += wi2_##k * h1k; bh0 += wh2_##k * h2k; pa0 += w1_##k * h1k; }
#define DMO(k) { float h1k = rdlane(hv, 32 + k); float h2k = rdlane(hv, k); \
                 bi1 += wi2_##k * h1k; bh1 += wh2_##k * h2k; pa1 += w1_##k * h1k; }
            REP16E(DME)
            REP15O(DMO)
#undef DME
#undef DMO
            float b = (bi0 + bi1) + (bh0 + bh1);
            float a = pa0 + pa1;
            {
                float z = isg ? (2.0f * b) : b;
                float s = 1.0f / (1.0f + __expf(-z));
                g2[pb][L] = isg ? (2.0f * s - 1.0f) : s;
            }
            {
                float z = isg ? (2.0f * a) : a;
                float s = 1.0f / (1.0f + __expf(-z));
                gA[pb][L] = isg ? (2.0f * s - 1.0f) : s;
            }
            __syncthreads();
            {
                const float* gsrc = selhi ? &gA[pb][0] : &g2[pb][0];
                float ig = gsrc[sidx];
                float fg = gsrc[sidx + 31];
                float gg = gsrc[sidx + 62];
                float og = gsrc[sidx + 93];
                cv = fg * cv + ig * gg;
                float e = __expf(-2.0f * cv);
                hv = og * (2.0f / (1.0f + e) - 1.0f);
            }
            if (L < HH_) h2a[((size_t)t * 64 + bb) * 32 + L] = hv;
        }

        // tail: L2(511)
        {
            float bi0 = b2c, bi1 = 0.0f, bh0 = 0.0f, bh1 = 0.0f;
#define DTE(k) { float h1k = rdlane(hv, 32 + k); float h2k = rdlane(hv, k); \
                 bi0 += wi2_##k * h1k; bh0 += wh2_##k * h2k; }
#define DTO(k) { float h1k = rdlane(hv, 32 + k); float h2k = rdlane(hv, k); \
                 bi1 += wi2_##k * h1k; bh1 += wh2_##k * h2k; }
            REP16E(DTE)
            REP15O(DTO)
#undef DTE
#undef DTO
            float b = (bi0 + bi1) + (bh0 + bh1);
            float z = isg ? (2.0f * b) : b;
            float s = 1.0f / (1.0f + __expf(-z));
            g2[1][L] = isg ? (2.0f * s - 1.0f) : s;
        }
        __syncthreads();
        {
            const float* gsrc = &g2[1][0];
            float ig = gsrc[sidx];
            float fg = gsrc[sidx + 31];
            float gg = gsrc[sidx + 62];
            float og = gsrc[sidx + 93];
            float cvn = fg * cv + ig * gg;
            float e = __expf(-2.0f * cvn);
            float hvn = og * (2.0f / (1.0f + e) - 1.0f);
            cv = selhi ? cv : cvn;
            hv = selhi ? hv : hvn;
        }
        if (L < HH_) h2a[((size_t)(TT_ - 1) * 64 + bb) * 32 + L] = hv;

        // future: needs Mv (16 producer blocks)
        while (aload_acq(mv_cnt) < 16) __builtin_amdgcn_s_sleep(2);
#define MLOAD(k) float m_##k = Mv[gc * 32 + k];
        REP31(MLOAD)
#undef MLOAD
        float m_31 = Mv[gc * 32 + 31];
#define MPIN(k) asm("" : "+v"(m_##k));
        REP31(MPIN)
#undef MPIN
        asm("" : "+v"(m_31));
        const float b1c = bih1[gc] + bhh1[gc];

        for (int sft = 0; sft < FUT_; sft++) {
            float pa0 = b1c + m_31, pa1 = 0.0f;
#define DFE(k) { float h2k = rdlane(hv, k); pa0 += m_##k * h2k; }
#define DFO(k) { float h2k = rdlane(hv, k); pa1 += m_##k * h2k; }
            REP16E(DFE)
            REP15O(DFO)
#undef DFE
#undef DFO
#define DGE(k) { float h1k = rdlane(hv, 32 + k); pa0 += w1_##k * h1k; }
#define DGO(k) { float h1k = rdlane(hv, 32 + k); pa1 += w1_##k * h1k; }
            REP16E(DGE)
            REP15O(DGO)
#undef DGE
#undef DGO
            {
                float a = pa0 + pa1;
                float z = isg ? (2.0f * a) : a;
                float s = 1.0f / (1.0f + __expf(-z));
                gA[0][L] = isg ? (2.0f * s - 1.0f) : s;
            }
            __syncthreads();
            {
                const float* gsrc = &gA[0][0];
                float ig = gsrc[sidx];
                float fg = gsrc[sidx + 31];
                float gg = gsrc[sidx + 62];
                float og = gsrc[sidx + 93];
                float cvn = fg * cv + ig * gg;
                float e = __expf(-2.0f * cvn);
                float hvn = og * (2.0f / (1.0f + e) - 1.0f);
                cv = selhi ? cvn : cv;
                hv = selhi ? hvn : hv;
            }
            float bi0 = b2c, bi1 = 0.0f, bh0 = 0.0f, bh1 = 0.0f;
#define DHE(k) { float h1k = rdlane(hv, 32 + k); float h2k = rdlane(hv, k); \
                 bi0 += wi2_##k * h1k; bh0 += wh2_##k * h2k; }
#define DHO(k) { float h1k = rdlane(hv, 32 + k); float h2k = rdlane(hv, k); \
                 bi1 += wi2_##k * h1k; bh1 += wh2_##k * h2k; }
            REP16E(DHE)
            REP15O(DHO)
#undef DHE
#undef DHO
            {
                float b = (bi0 + bi1) + (bh0 + bh1);
                float z = isg ? (2.0f * b) : b;
                float s = 1.0f / (1.0f + __expf(-z));
                g2[0][L] = isg ? (2.0f * s - 1.0f) : s;
            }
            __syncthreads();
            {
                const float* gsrc = &g2[0][0];
                float ig = gsrc[sidx];
                float fg = gsrc[sidx + 31];
                float gg = gsrc[sidx + 62];
                float og = gsrc[sidx + 93];
                float cvn = fg * cv + ig * gg;
                float e = __expf(-2.0f * cvn);
                float hvn = og * (2.0f / (1.0f + e) - 1.0f);
                cv = selhi ? cv : cvn;
                hv = selhi ? hv : hvn;
            }
            if (L < HH_) h2a[((size_t)(TT_ + sft) * 64 + bb) * 32 + L] = hv;
        }
    }
}

// ---------------- K3 v2: output linear, 32 rows/block (R9 verified) ----------------
__global__ __launch_bounds__(256) void k3_outlin(
    const float* __restrict__ h2a,   // [528*64][32]
    const float* __restrict__ WT,    // [31][1024]
    const float* __restrict__ blin,  // [1024]
    float* __restrict__ out)         // [B][528][1024] fp32
{
    __shared__ __align__(16) float hl[32][32];
    const int tid = threadIdx.x;
    const int m0  = blockIdx.x * 32;
#pragma unroll
    for (int p = 0; p < 4; p++) {
        int i = tid + p * 256;
        int r = i >> 5, k = i & 31;
        hl[r][k] = h2a[(size_t)(m0 + r) * 32 + k];
    }
    __syncthreads();
    const int c0 = tid * 4;
    float4 bl = *(const float4*)(blin + c0);
    float4 acc[32];
#pragma unroll
    for (int r = 0; r < 32; r++) acc[r] = bl;
    for (int k = 0; k < 31; k++) {
        float4 wv = *(const float4*)(WT + k * 1024 + c0);
#pragma unroll
        for (int r = 0; r < 32; r++) {
            float h = hl[r][k];
            acc[r].x += h * wv.x; acc[r].y += h * wv.y;
            acc[r].z += h * wv.z; acc[r].w += h * wv.w;
        }
    }
    const int t  = m0 >> 6;
    const int b0 = m0 & 63;
#pragma unroll
    for (int r = 0; r < 32; r++) {
        int b = b0 + r;
        *(float4*)(out + (size_t)b * OUT_ROW_ + (size_t)t * FF_ + c0) = acc[r];
    }
}

extern "C" void kernel_launch(void* const* d_in, const int* in_sizes, int n_in,
                              void* d_out, int out_size, void* d_ws, size_t ws_size,
                              hipStream_t stream) {
    (void)in_sizes; (void)n_in; (void)out_size; (void)ws_size;
    const float* X    = (const float*)d_in[0];
    const float* Wih1 = (const float*)d_in[1];
    const float* Whh1 = (const float*)d_in[2];
    const float* bih1 = (const float*)d_in[3];
    const float* bhh1 = (const float*)d_in[4];
    const float* Wih2 = (const float*)d_in[5];
    const float* Whh2 = (const float*)d_in[6];
    const float* bih2 = (const float*)d_in[7];
    const float* bhh2 = (const float*)d_in[8];
    const float* Wlin = (const float*)d_in[9];
    const float* blin = (const float*)d_in[10];
    // d_in[11] = future = 16 (constant for this problem)

    float* ws   = (float*)d_ws;
    float* pre1 = ws + PRE1_OFF;
    float* h2a  = ws + H2A_OFF;
    float* WT   = ws + WT_OFF;
    float* Mv   = ws + MV_OFF;
    int*   flg  = (int*)(ws + FLG_OFF);
    float* out  = (float*)d_out;

    hipLaunchKernelGGL(k_zero,  dim3(1),       dim3(256), 0, stream, flg);
    hipLaunchKernelGGL(k_fused, dim3(NBLK),    dim3(256), 0, stream,
                       X, Wih1, Whh1, Wih2, Whh2, bih1, bhh1, bih2, bhh2,
                       Wlin, blin, pre1, h2a, WT, Mv, flg);
    hipLaunchKernelGGL(k3_outlin, dim3(TTOT_*2), dim3(256), 0, stream, h2a, WT, blin, out);
}